// Round 8
// baseline (119.236 us; speedup 1.0000x reference)
//
#include <hip/hip_runtime.h>
#include <hip/hip_bf16.h>

// Problem constants (from reference)
#define B_GRAPHS 16384
#define NODES_PER_G 50
#define REPR 128          // (1+L)*EMB
#define PFEAT 1280
#define FEAT 200
#define EMB 32
#define P_ROWS 2000
#define D_ROWS 10000

#define NPF (P_ROWS / 8)            // 250 protein-fuse blocks
#define NDF (D_ROWS / 8)            // 1250 drug-fuse blocks
#define NFUSE (NPF + NDF)           // 1500
#define NPOOL (B_GRAPHS)            // 16384 pool blocks (1 graph per BLOCK)
#define NTOT (NPOOL + NFUSE)        // 17884

// ws layout (floats): [0 .. 2*P_ROWS) fuse1-dot [P][2];
//                     [2*P_ROWS ..) fuse2-dot [D][2]

// ---------------------------------------------------------------------------
// Merged kernel, Bresenham-interleaved roles. Pool path rebuilt for DRAM
// page locality: ONE BLOCK PER GRAPH — 256 threads march the graph's
// 25.6 KB region in 4 KB contiguous block-chunks (8 rows per chunk), all
// 7 thread-loads issued before use (whole graph in flight). This cuts
// device-wide concurrent DRAM streams ~8x vs group-per-graph (2048 resident
// block-streams of 4 KB bursts instead of 16384 streams of 512 B bursts).
//   thread t, step i: reads nr4[g*1600 + i*256 + t]  (rows 8i..8i+7)
//   tail step: threads 0..63 read rows 48,49.
//   thread t accumulates col (t&31); LDS reduce folds the 8 row-classes.
// ---------------------------------------------------------------------------
__global__ __launch_bounds__(256) void merged_kernel(
    const float* __restrict__ nr,        // node_repr [N][128]
    const float* __restrict__ profeat,   // [P][1280]
    const float* __restrict__ drugfeat,  // [D][200]
    const float* __restrict__ W1p,       // [1280][32]
    const float* __restrict__ b1p,       // [32]
    const float* __restrict__ W2p,       // [32][32]
    const float* __restrict__ W1,        // [200][32]
    const float* __restrict__ b1,        // [32]
    const float* __restrict__ W2,        // [32][32]
    const float* __restrict__ fcW,       // [448][2]
    const float* __restrict__ b2p,       // [32]
    const float* __restrict__ b2,        // [32]
    float*       __restrict__ f1out,     // [P][2]
    float*       __restrict__ f2out,     // [D][2]
    float*       __restrict__ out)       // [B][2] (partial)
{
    __shared__ float4 sm[256];
    __shared__ float4 sht[64];           // head cols (0..31), tail cols (32..63)

    const int bid = blockIdx.x;
    const int Fb  = (int)(((long)bid * NFUSE) / NTOT);
    const int Fb1 = (int)(((long)(bid + 1) * NFUSE) / NTOT);

    if (Fb1 == Fb) {
        // ---------------- graph pooling: 1 block = 1 graph ----------------
        const int t = threadIdx.x;
        const int g = bid - Fb;          // 0..16383
        const float4* nr4 = (const float4*)nr;
        const long base4 = (long)g * (NODES_PER_G * REPR / 4);  // g*1600

        // issue the whole graph: 6 full 4KB chunks + 1KB tail chunk
        float4 f0 = nr4[base4 + 0 * 256 + t];
        float4 f1 = nr4[base4 + 1 * 256 + t];
        float4 f2 = nr4[base4 + 2 * 256 + t];
        float4 f3 = nr4[base4 + 3 * 256 + t];
        float4 f4 = nr4[base4 + 4 * 256 + t];
        float4 f5 = nr4[base4 + 5 * 256 + t];
        float4 ft;
        if (t < 64) {
            ft = nr4[base4 + 1536 + t];  // rows 48,49
        } else {
            ft.x = ft.y = ft.z = ft.w = 0.f;
        }

        if (t < 64) sht[t] = f0;         // step-0 rows 0,1 = head,tail

        float4 acc;
        acc.x = ((f0.x + f1.x) + (f2.x + f3.x)) + ((f4.x + f5.x) + ft.x);
        acc.y = ((f0.y + f1.y) + (f2.y + f3.y)) + ((f4.y + f5.y) + ft.y);
        acc.z = ((f0.z + f1.z) + (f2.z + f3.z)) + ((f4.z + f5.z) + ft.z);
        acc.w = ((f0.w + f1.w) + (f2.w + f3.w)) + ((f4.w + f5.w) + ft.w);
        sm[t] = acc;
        __syncthreads();

        if (t < 32) {
            float4 pool = sm[t];
            #pragma unroll
            for (int j = 1; j < 8; ++j) {
                float4 v = sm[t + 32 * j];
                pool.x += v.x; pool.y += v.y; pool.z += v.z; pool.w += v.w;
            }
            float4 head4 = sht[t];
            float4 tail4 = sht[32 + t];

            const float4* fcW4 = (const float4*)fcW;
            float4 wg0 = fcW4[t * 2 + 0],       wg1 = fcW4[t * 2 + 1];
            float4 wh0 = fcW4[64 + t * 2 + 0],  wh1 = fcW4[64 + t * 2 + 1];
            float4 wt0 = fcW4[128 + t * 2 + 0], wt1 = fcW4[128 + t * 2 + 1];

            const float inv50 = 1.0f / (float)NODES_PER_G;
            float p0 = inv50 * (pool.x * wg0.x + pool.y * wg0.z + pool.z * wg1.x + pool.w * wg1.z)
                     + head4.x * wh0.x + head4.y * wh0.z + head4.z * wh1.x + head4.w * wh1.z
                     + tail4.x * wt0.x + tail4.y * wt0.z + tail4.z * wt1.x + tail4.w * wt1.z;
            float p1 = inv50 * (pool.x * wg0.y + pool.y * wg0.w + pool.z * wg1.y + pool.w * wg1.w)
                     + head4.x * wh0.y + head4.y * wh0.w + head4.z * wh1.y + head4.w * wh1.w
                     + tail4.x * wt0.y + tail4.y * wt0.w + tail4.z * wt1.y + tail4.w * wt1.w;

            // constant bias pieces: b2p·fcW[384..416) and b2·fcW[416..448)
            {
                float2 fw1 = *(const float2*)(fcW + (384 + t) * 2);
                float2 fw2 = *(const float2*)(fcW + (416 + t) * 2);
                float bb1 = b2p[t], bb2 = b2[t];
                p0 = fmaf(bb1, fw1.x, fmaf(bb2, fw2.x, p0));
                p1 = fmaf(bb1, fw1.y, fmaf(bb2, fw2.y, p1));
            }

            for (int m = 16; m >= 1; m >>= 1) {
                p0 += __shfl_xor(p0, m, 32);
                p1 += __shfl_xor(p1, m, 32);
            }
            if (t == 0) {
                out[g * 2 + 0] = p0;   // partial: fuse dots + fc_b in finalize
                out[g * 2 + 1] = p1;
            }
        }
    } else if (Fb < NPF) {
        // ---------------- protein fuse ---------------- [R3/R5 verbatim]
        const int grp  = threadIdx.x >> 5;
        const int lane = threadIdx.x & 31;
        const int p = Fb * 8 + grp;
        float m0 = 0.f, m1 = 0.f;
        #pragma unroll
        for (int k = 0; k < 32; ++k) {
            float w = W2p[lane * 32 + k];
            float2 fw = *(const float2*)(fcW + (384 + k) * 2);
            m0 = fmaf(w, fw.x, m0);
            m1 = fmaf(w, fw.y, m1);
        }
        const float4* pf4 = (const float4*)(profeat + (long)p * PFEAT);
        float a0 = 0.f, a1 = 0.f, a2 = 0.f, a3 = 0.f;
        #pragma unroll 4
        for (int q = 0; q < PFEAT / 4; q += 4) {
            float4 f0 = pf4[q], f1 = pf4[q + 1], f2 = pf4[q + 2], f3 = pf4[q + 3];
            int k = q * 4;
            a0 = fmaf(f0.x, W1p[(k + 0) * 32 + lane], a0);
            a0 = fmaf(f0.y, W1p[(k + 1) * 32 + lane], a0);
            a0 = fmaf(f0.z, W1p[(k + 2) * 32 + lane], a0);
            a0 = fmaf(f0.w, W1p[(k + 3) * 32 + lane], a0);
            a1 = fmaf(f1.x, W1p[(k + 4) * 32 + lane], a1);
            a1 = fmaf(f1.y, W1p[(k + 5) * 32 + lane], a1);
            a1 = fmaf(f1.z, W1p[(k + 6) * 32 + lane], a1);
            a1 = fmaf(f1.w, W1p[(k + 7) * 32 + lane], a1);
            a2 = fmaf(f2.x, W1p[(k + 8) * 32 + lane], a2);
            a2 = fmaf(f2.y, W1p[(k + 9) * 32 + lane], a2);
            a2 = fmaf(f2.z, W1p[(k + 10) * 32 + lane], a2);
            a2 = fmaf(f2.w, W1p[(k + 11) * 32 + lane], a2);
            a3 = fmaf(f3.x, W1p[(k + 12) * 32 + lane], a3);
            a3 = fmaf(f3.y, W1p[(k + 13) * 32 + lane], a3);
            a3 = fmaf(f3.z, W1p[(k + 14) * 32 + lane], a3);
            a3 = fmaf(f3.w, W1p[(k + 15) * 32 + lane], a3);
        }
        float h = fmaxf((a0 + a1) + (a2 + a3) + b1p[lane], 0.f);
        float p0 = h * m0, p1 = h * m1;
        for (int m = 16; m >= 1; m >>= 1) {
            p0 += __shfl_xor(p0, m, 32);
            p1 += __shfl_xor(p1, m, 32);
        }
        if (lane == 0) {
            f1out[p * 2 + 0] = p0;
            f1out[p * 2 + 1] = p1;
        }
    } else {
        // ---------------- drug fuse ---------------- [R3/R5 verbatim]
        const int grp  = threadIdx.x >> 5;
        const int lane = threadIdx.x & 31;
        const int d = (Fb - NPF) * 8 + grp;
        float m0 = 0.f, m1 = 0.f;
        #pragma unroll
        for (int k = 0; k < 32; ++k) {
            float w = W2[lane * 32 + k];
            float2 fw = *(const float2*)(fcW + (416 + k) * 2);
            m0 = fmaf(w, fw.x, m0);
            m1 = fmaf(w, fw.y, m1);
        }
        const float4* df4 = (const float4*)(drugfeat + (long)d * FEAT);
        float a0 = 0.f, a1 = 0.f;
        #pragma unroll 5
        for (int q = 0; q < FEAT / 4; q += 2) {
            float4 f0 = df4[q], f1 = df4[q + 1];
            int k = q * 4;
            a0 = fmaf(f0.x, W1[(k + 0) * 32 + lane], a0);
            a0 = fmaf(f0.y, W1[(k + 1) * 32 + lane], a0);
            a0 = fmaf(f0.z, W1[(k + 2) * 32 + lane], a0);
            a0 = fmaf(f0.w, W1[(k + 3) * 32 + lane], a0);
            a1 = fmaf(f1.x, W1[(k + 4) * 32 + lane], a1);
            a1 = fmaf(f1.y, W1[(k + 5) * 32 + lane], a1);
            a1 = fmaf(f1.z, W1[(k + 6) * 32 + lane], a1);
            a1 = fmaf(f1.w, W1[(k + 7) * 32 + lane], a1);
        }
        float h = fmaxf(a0 + a1 + b1[lane], 0.f);
        float p0 = h * m0, p1 = h * m1;
        for (int m = 16; m >= 1; m >>= 1) {
            p0 += __shfl_xor(p0, m, 32);
            p1 += __shfl_xor(p1, m, 32);
        }
        if (lane == 0) {
            f2out[d * 2 + 0] = p0;
            f2out[d * 2 + 1] = p1;
        }
    }
}

// ---------------------------------------------------------------------------
// Finalize: one thread per graph. Dedup-table gathers + constant bias.
// ---------------------------------------------------------------------------
__global__ __launch_bounds__(256) void finalize_kernel(
    const int*   __restrict__ head_ids,  // [B]
    const int*   __restrict__ tail_ids,  // [B]
    const int*   __restrict__ node_idx,  // [N]
    const int*   __restrict__ proind,    // [I]
    const int*   __restrict__ drugind,   // [I]
    const float* __restrict__ f1out,     // [P][2]
    const float* __restrict__ f2out,     // [D][2]
    const float* __restrict__ fcb,       // [2]
    float*       __restrict__ out)       // [B][2]
{
    const int g = blockIdx.x * 256 + threadIdx.x;
    if (g >= B_GRAPHS) return;
    const int prow = proind[node_idx[head_ids[g]]];
    const int drow = drugind[node_idx[tail_ids[g]]];
    const float2 f1v = *(const float2*)(f1out + prow * 2);
    const float2 f2v = *(const float2*)(f2out + drow * 2);
    float2 o = *(float2*)(out + g * 2);
    o.x += f1v.x + f2v.x + fcb[0];
    o.y += f1v.y + f2v.y + fcb[1];
    *(float2*)(out + g * 2) = o;
}

extern "C" void kernel_launch(void* const* d_in, const int* in_sizes, int n_in,
                              void* d_out, int out_size, void* d_ws, size_t ws_size,
                              hipStream_t stream) {
    const float* node_repr = (const float*)d_in[0];
    const float* profeat   = (const float*)d_in[1];
    const float* drugfeat  = (const float*)d_in[2];
    const float* W1p       = (const float*)d_in[3];
    const float* b1p       = (const float*)d_in[4];
    const float* W2p       = (const float*)d_in[5];
    const float* b2p       = (const float*)d_in[6];
    const float* W1        = (const float*)d_in[7];
    const float* b1        = (const float*)d_in[8];
    const float* W2        = (const float*)d_in[9];
    const float* b2        = (const float*)d_in[10];
    const float* fc_W      = (const float*)d_in[11];
    const float* fc_b      = (const float*)d_in[12];
    // d_in[13] = graph_ids (unused: blocks are contiguous, 50 nodes each)
    const int* head_ids    = (const int*)d_in[14];
    const int* tail_ids    = (const int*)d_in[15];
    const int* node_idx    = (const int*)d_in[16];
    const int* proind      = (const int*)d_in[17];
    const int* drugind     = (const int*)d_in[18];

    float* f1out = (float*)d_ws;                 // 2000*2 floats
    float* f2out = (float*)d_ws + 2 * P_ROWS;    // 10000*2 floats
    float* out   = (float*)d_out;

    hipLaunchKernelGGL(merged_kernel, dim3(NTOT), dim3(256), 0, stream,
                       node_repr, profeat, drugfeat, W1p, b1p, W2p, W1, b1, W2,
                       fc_W, b2p, b2, f1out, f2out, out);

    hipLaunchKernelGGL(finalize_kernel, dim3(B_GRAPHS / 256), dim3(256), 0, stream,
                       head_ids, tail_ids, node_idx, proind, drugind,
                       f1out, f2out, fc_b, out);
}

// Round 9
// 113.781 us; speedup vs baseline: 1.0479x; 1.0479x over previous
//
#include <hip/hip_runtime.h>
#include <hip/hip_bf16.h>

// Problem constants (from reference)
#define B_GRAPHS 16384
#define NODES_PER_G 50
#define REPR 128          // (1+L)*EMB
#define PFEAT 1280
#define FEAT 200
#define EMB 32
#define P_ROWS 2000
#define D_ROWS 10000

#define NPF (P_ROWS / 8)            // 250 protein-fuse blocks
#define NDF (D_ROWS / 8)            // 1250 drug-fuse blocks
#define NFUSE (NPF + NDF)           // 1500
#define NPOOL (B_GRAPHS / 4)        // 4096 pool blocks (1 graph per wave)
#define NTOT (NPOOL + NFUSE)        // 5596

// Graph region: 50 rows x 512 B = 25600 B = 25 chunks of 1 KB (2 rows each).
// Chunk cc holds rows 2cc (lanes 0-31) and 2cc+1 (lanes 32-63), 16 B/lane.

#define GLOAD_LDS(gp, lp)                                                     \
    __builtin_amdgcn_global_load_lds(                                         \
        (const __attribute__((address_space(1))) float*)(gp),                 \
        (__attribute__((address_space(3))) float*)(lp), 16, 0, 0)

// ---------------------------------------------------------------------------
// Merged kernel, Bresenham-interleaved roles (proven R5). Pool path rebuilt
// on the direct-to-LDS DMA pipeline: each WAVE owns one graph, stages it in
// 5 tiles of 5 chunks (5 KB) via global_load_lds (fire-and-forget, no VGPR
// writeback), double-buffered, counted s_waitcnt vmcnt(5) (never 0 in the
// steady loop), reduces each tile from LDS. Wave-private -> no barriers.
// LDS: 4 waves x 2 bufs x 5 KB = 40 KB/block -> 4 blocks/CU, 16 waves/CU.
// ---------------------------------------------------------------------------
__global__ __launch_bounds__(256) void merged_kernel(
    const float* __restrict__ nr,        // node_repr [N][128]
    const float* __restrict__ profeat,   // [P][1280]
    const float* __restrict__ drugfeat,  // [D][200]
    const float* __restrict__ W1p,       // [1280][32]
    const float* __restrict__ b1p,       // [32]
    const float* __restrict__ W2p,       // [32][32]
    const float* __restrict__ W1,        // [200][32]
    const float* __restrict__ b1,        // [32]
    const float* __restrict__ W2,        // [32][32]
    const float* __restrict__ fcW,       // [448][2]
    const float* __restrict__ b2p,       // [32]
    const float* __restrict__ b2,        // [32]
    float*       __restrict__ f1out,     // [P][2]
    float*       __restrict__ f2out,     // [D][2]
    float*       __restrict__ out)       // [B][2] (partial)
{
    __shared__ float lds[4][2][1280];    // [wave][buf][5 chunks x 256 floats]

    const int bid = blockIdx.x;
    const int Fb  = (int)(((long)bid * NFUSE) / NTOT);
    const int Fb1 = (int)(((long)(bid + 1) * NFUSE) / NTOT);

    if (Fb1 == Fb) {
        // ------------- graph pooling: 1 wave = 1 graph, LDS-DMA staged -----
        const int w   = threadIdx.x >> 6;        // wave in block 0..3
        const int l   = threadIdx.x & 63;        // lane
        const int col = l & 31;                  // float4-column within row
        const int g   = (bid - Fb) * 4 + w;

        const float* gbase = nr + (long)g * (NODES_PER_G * REPR);  // g*6400 floats

        // prologue: stage tile 0 (chunks 0..4) into buf 0
        #pragma unroll
        for (int c = 0; c < 5; ++c)
            GLOAD_LDS(gbase + c * 256 + l * 4, &lds[w][0][c * 256]);

        float4 sp;                                // head/tail row (chunk 0)
        float4 a0, a1;
        a0.x = a0.y = a0.z = a0.w = 0.f;
        a1.x = a1.y = a1.z = a1.w = 0.f;

        #pragma unroll
        for (int tt = 0; tt < 5; ++tt) {
            if (tt < 4) {
                // stage next tile into the other buffer (fire-and-forget)
                const float* gt = gbase + (tt + 1) * 1280;
                #pragma unroll
                for (int c = 0; c < 5; ++c)
                    GLOAD_LDS(gt + c * 256 + l * 4, &lds[w][(tt + 1) & 1][c * 256]);
                // counted wait: oldest 5 (current tile) complete; next 5 stay in flight
                asm volatile("s_waitcnt vmcnt(5)" ::: "memory");
            } else {
                asm volatile("s_waitcnt vmcnt(0)" ::: "memory");
            }
            const float* lb = &lds[w][tt & 1][0];
            #pragma unroll
            for (int c = 0; c < 5; ++c) {
                float4 v = *(const float4*)(lb + c * 256 + l * 4);
                if (tt == 0 && c == 0) sp = v;
                if (c & 1) {
                    a1.x += v.x; a1.y += v.y; a1.z += v.z; a1.w += v.w;
                } else {
                    a0.x += v.x; a0.y += v.y; a0.z += v.z; a0.w += v.w;
                }
            }
        }
        float4 pool;
        pool.x = a0.x + a1.x;
        pool.y = a0.y + a1.y;
        pool.z = a0.z + a1.z;
        pool.w = a0.w + a1.w;

        // ---- epilogue (R7-verified form): per-parity slices, 64-lane reduce
        const float4* fcW4 = (const float4*)fcW;
        float4 wg0 = fcW4[col * 2 + 0], wg1 = fcW4[col * 2 + 1];
        float4 wsp0, wsp1;
        float2 fwb;
        float bw;
        if (l < 32) {   // head half: wh slice + b2p bias term
            wsp0 = fcW4[64 + col * 2 + 0];
            wsp1 = fcW4[64 + col * 2 + 1];
            fwb  = *(const float2*)(fcW + (384 + col) * 2);
            bw   = b2p[col];
        } else {        // tail half: wt slice + b2 bias term
            wsp0 = fcW4[128 + col * 2 + 0];
            wsp1 = fcW4[128 + col * 2 + 1];
            fwb  = *(const float2*)(fcW + (416 + col) * 2);
            bw   = b2[col];
        }

        const float inv50 = 1.0f / (float)NODES_PER_G;
        float p0 = inv50 * (pool.x * wg0.x + pool.y * wg0.z + pool.z * wg1.x + pool.w * wg1.z)
                 + sp.x * wsp0.x + sp.y * wsp0.z + sp.z * wsp1.x + sp.w * wsp1.z
                 + bw * fwb.x;
        float p1 = inv50 * (pool.x * wg0.y + pool.y * wg0.w + pool.z * wg1.y + pool.w * wg1.w)
                 + sp.x * wsp0.y + sp.y * wsp0.w + sp.z * wsp1.y + sp.w * wsp1.w
                 + bw * fwb.y;

        for (int m = 32; m >= 1; m >>= 1) {
            p0 += __shfl_xor(p0, m, 64);
            p1 += __shfl_xor(p1, m, 64);
        }
        if (l == 0) {
            out[g * 2 + 0] = p0;   // partial: fuse dots + fc_b added by finalize
            out[g * 2 + 1] = p1;
        }
    } else if (Fb < NPF) {
        // ---------------- protein fuse ---------------- [R3/R5 verbatim]
        const int grp  = threadIdx.x >> 5;
        const int lane = threadIdx.x & 31;
        const int p = Fb * 8 + grp;
        float m0 = 0.f, m1 = 0.f;
        #pragma unroll
        for (int k = 0; k < 32; ++k) {
            float w = W2p[lane * 32 + k];
            float2 fw = *(const float2*)(fcW + (384 + k) * 2);
            m0 = fmaf(w, fw.x, m0);
            m1 = fmaf(w, fw.y, m1);
        }
        const float4* pf4 = (const float4*)(profeat + (long)p * PFEAT);
        float a0 = 0.f, a1 = 0.f, a2 = 0.f, a3 = 0.f;
        #pragma unroll 4
        for (int q = 0; q < PFEAT / 4; q += 4) {
            float4 f0 = pf4[q], f1 = pf4[q + 1], f2 = pf4[q + 2], f3 = pf4[q + 3];
            int k = q * 4;
            a0 = fmaf(f0.x, W1p[(k + 0) * 32 + lane], a0);
            a0 = fmaf(f0.y, W1p[(k + 1) * 32 + lane], a0);
            a0 = fmaf(f0.z, W1p[(k + 2) * 32 + lane], a0);
            a0 = fmaf(f0.w, W1p[(k + 3) * 32 + lane], a0);
            a1 = fmaf(f1.x, W1p[(k + 4) * 32 + lane], a1);
            a1 = fmaf(f1.y, W1p[(k + 5) * 32 + lane], a1);
            a1 = fmaf(f1.z, W1p[(k + 6) * 32 + lane], a1);
            a1 = fmaf(f1.w, W1p[(k + 7) * 32 + lane], a1);
            a2 = fmaf(f2.x, W1p[(k + 8) * 32 + lane], a2);
            a2 = fmaf(f2.y, W1p[(k + 9) * 32 + lane], a2);
            a2 = fmaf(f2.z, W1p[(k + 10) * 32 + lane], a2);
            a2 = fmaf(f2.w, W1p[(k + 11) * 32 + lane], a2);
            a3 = fmaf(f3.x, W1p[(k + 12) * 32 + lane], a3);
            a3 = fmaf(f3.y, W1p[(k + 13) * 32 + lane], a3);
            a3 = fmaf(f3.z, W1p[(k + 14) * 32 + lane], a3);
            a3 = fmaf(f3.w, W1p[(k + 15) * 32 + lane], a3);
        }
        float h = fmaxf((a0 + a1) + (a2 + a3) + b1p[lane], 0.f);
        float p0 = h * m0, p1 = h * m1;
        for (int m = 16; m >= 1; m >>= 1) {
            p0 += __shfl_xor(p0, m, 32);
            p1 += __shfl_xor(p1, m, 32);
        }
        if (lane == 0) {
            f1out[p * 2 + 0] = p0;
            f1out[p * 2 + 1] = p1;
        }
    } else {
        // ---------------- drug fuse ---------------- [R3/R5 verbatim]
        const int grp  = threadIdx.x >> 5;
        const int lane = threadIdx.x & 31;
        const int d = (Fb - NPF) * 8 + grp;
        float m0 = 0.f, m1 = 0.f;
        #pragma unroll
        for (int k = 0; k < 32; ++k) {
            float w = W2[lane * 32 + k];
            float2 fw = *(const float2*)(fcW + (416 + k) * 2);
            m0 = fmaf(w, fw.x, m0);
            m1 = fmaf(w, fw.y, m1);
        }
        const float4* df4 = (const float4*)(drugfeat + (long)d * FEAT);
        float a0 = 0.f, a1 = 0.f;
        #pragma unroll 5
        for (int q = 0; q < FEAT / 4; q += 2) {
            float4 f0 = df4[q], f1 = df4[q + 1];
            int k = q * 4;
            a0 = fmaf(f0.x, W1[(k + 0) * 32 + lane], a0);
            a0 = fmaf(f0.y, W1[(k + 1) * 32 + lane], a0);
            a0 = fmaf(f0.z, W1[(k + 2) * 32 + lane], a0);
            a0 = fmaf(f0.w, W1[(k + 3) * 32 + lane], a0);
            a1 = fmaf(f1.x, W1[(k + 4) * 32 + lane], a1);
            a1 = fmaf(f1.y, W1[(k + 5) * 32 + lane], a1);
            a1 = fmaf(f1.z, W1[(k + 6) * 32 + lane], a1);
            a1 = fmaf(f1.w, W1[(k + 7) * 32 + lane], a1);
        }
        float h = fmaxf(a0 + a1 + b1[lane], 0.f);
        float p0 = h * m0, p1 = h * m1;
        for (int m = 16; m >= 1; m >>= 1) {
            p0 += __shfl_xor(p0, m, 32);
            p1 += __shfl_xor(p1, m, 32);
        }
        if (lane == 0) {
            f2out[d * 2 + 0] = p0;
            f2out[d * 2 + 1] = p1;
        }
    }
}

// ---------------------------------------------------------------------------
// Finalize: one thread per graph. Dedup-table gathers + constant bias.
// ---------------------------------------------------------------------------
__global__ __launch_bounds__(256) void finalize_kernel(
    const int*   __restrict__ head_ids,  // [B]
    const int*   __restrict__ tail_ids,  // [B]
    const int*   __restrict__ node_idx,  // [N]
    const int*   __restrict__ proind,    // [I]
    const int*   __restrict__ drugind,   // [I]
    const float* __restrict__ f1out,     // [P][2]
    const float* __restrict__ f2out,     // [D][2]
    const float* __restrict__ fcb,       // [2]
    float*       __restrict__ out)       // [B][2]
{
    const int g = blockIdx.x * 256 + threadIdx.x;
    if (g >= B_GRAPHS) return;
    const int prow = proind[node_idx[head_ids[g]]];
    const int drow = drugind[node_idx[tail_ids[g]]];
    const float2 f1v = *(const float2*)(f1out + prow * 2);
    const float2 f2v = *(const float2*)(f2out + drow * 2);
    float2 o = *(float2*)(out + g * 2);
    o.x += f1v.x + f2v.x + fcb[0];
    o.y += f1v.y + f2v.y + fcb[1];
    *(float2*)(out + g * 2) = o;
}

extern "C" void kernel_launch(void* const* d_in, const int* in_sizes, int n_in,
                              void* d_out, int out_size, void* d_ws, size_t ws_size,
                              hipStream_t stream) {
    const float* node_repr = (const float*)d_in[0];
    const float* profeat   = (const float*)d_in[1];
    const float* drugfeat  = (const float*)d_in[2];
    const float* W1p       = (const float*)d_in[3];
    const float* b1p       = (const float*)d_in[4];
    const float* W2p       = (const float*)d_in[5];
    const float* b2p       = (const float*)d_in[6];
    const float* W1        = (const float*)d_in[7];
    const float* b1        = (const float*)d_in[8];
    const float* W2        = (const float*)d_in[9];
    const float* b2        = (const float*)d_in[10];
    const float* fc_W      = (const float*)d_in[11];
    const float* fc_b      = (const float*)d_in[12];
    // d_in[13] = graph_ids (unused: blocks are contiguous, 50 nodes each)
    const int* head_ids    = (const int*)d_in[14];
    const int* tail_ids    = (const int*)d_in[15];
    const int* node_idx    = (const int*)d_in[16];
    const int* proind      = (const int*)d_in[17];
    const int* drugind     = (const int*)d_in[18];

    float* f1out = (float*)d_ws;                 // 2000*2 floats
    float* f2out = (float*)d_ws + 2 * P_ROWS;    // 10000*2 floats
    float* out   = (float*)d_out;

    hipLaunchKernelGGL(merged_kernel, dim3(NTOT), dim3(256), 0, stream,
                       node_repr, profeat, drugfeat, W1p, b1p, W2p, W1, b1, W2,
                       fc_W, b2p, b2, f1out, f2out, out);

    hipLaunchKernelGGL(finalize_kernel, dim3(B_GRAPHS / 256), dim3(256), 0, stream,
                       head_ids, tail_ids, node_idx, proind, drugind,
                       f1out, f2out, fc_b, out);
}

// Round 10
// 107.275 us; speedup vs baseline: 1.1115x; 1.0607x over previous
//
#include <hip/hip_runtime.h>
#include <hip/hip_bf16.h>

// Problem constants (from reference)
#define B_GRAPHS 16384
#define NODES_PER_G 50
#define REPR 128          // (1+L)*EMB
#define PFEAT 1280
#define FEAT 200
#define EMB 32
#define P_ROWS 2000
#define D_ROWS 10000

#define NPF (P_ROWS / 8)            // 250 protein-fuse blocks
#define NDF (D_ROWS / 8)            // 1250 drug-fuse blocks
#define NFUSE (NPF + NDF)           // 1500
#define NPOOL (B_GRAPHS / 8)        // 2048 pool blocks
#define NTOT (NPOOL + NFUSE)        // 3548

// ws layout (floats): [0 .. 2*P_ROWS) fuse1-dot [P][2];
//                     [2*P_ROWS ..) fuse2-dot [D][2]

// ---------------------------------------------------------------------------
// R5 revert (best measured: 107.3 us). Merged kernel with Bresenham-
// interleaved block roles: fuse blocks spread uniformly through dispatch
// order so their L2/VALU-bound work hides under the pool HBM stream.
//   F(b) = floor(b*NFUSE/NTOT); block b is fuse iff F(b+1)>F(b).
// Pool: one 32-lane group per graph, 8 graphs/block, 2-acc unroll-8 loop.
// Evidence from R5-R9: read-stream rate (~4.5 TB/s) is invariant across
// segment size / stream count / ILP depth / LDS-DMA — per-CU outstanding-
// miss limit; this shape is at the practical read ceiling.
// ---------------------------------------------------------------------------
__global__ __launch_bounds__(256) void merged_kernel(
    const float* __restrict__ nr,        // node_repr [N][128]
    const float* __restrict__ profeat,   // [P][1280]
    const float* __restrict__ drugfeat,  // [D][200]
    const float* __restrict__ W1p,       // [1280][32]
    const float* __restrict__ b1p,       // [32]
    const float* __restrict__ W2p,       // [32][32]
    const float* __restrict__ W1,        // [200][32]
    const float* __restrict__ b1,        // [32]
    const float* __restrict__ W2,        // [32][32]
    const float* __restrict__ fcW,       // [448][2]
    const float* __restrict__ b2p,       // [32]
    const float* __restrict__ b2,        // [32]
    float*       __restrict__ f1out,     // [P][2]
    float*       __restrict__ f2out,     // [D][2]
    float*       __restrict__ out)       // [B][2] (partial)
{
    const int grp  = threadIdx.x >> 5;
    const int lane = threadIdx.x & 31;
    const int bid  = blockIdx.x;

    const int Fb  = (int)(((long)bid * NFUSE) / NTOT);
    const int Fb1 = (int)(((long)(bid + 1) * NFUSE) / NTOT);

    if (Fb1 == Fb) {
        // ---------------- graph pooling (pure stream) ----------------
        const int g = (bid - Fb) * 8 + grp;
        const float4* nr4 = (const float4*)nr;
        const long base4 = (long)g * (NODES_PER_G * REPR / 4);  // g*1600

        float4 head4 = nr4[base4 + 0 * 32 + lane];
        float4 tail4 = nr4[base4 + 1 * 32 + lane];
        float4 s0, s1;
        s0.x = s0.y = s0.z = s0.w = 0.f;
        s1.x = s1.y = s1.z = s1.w = 0.f;
        #pragma unroll 8
        for (int i = 2; i < NODES_PER_G; i += 2) {
            float4 fa = nr4[base4 + i * 32 + lane];
            float4 fb = nr4[base4 + (i + 1) * 32 + lane];
            s0.x += fa.x; s0.y += fa.y; s0.z += fa.z; s0.w += fa.w;
            s1.x += fb.x; s1.y += fb.y; s1.z += fb.z; s1.w += fb.w;
        }
        float4 pool;
        pool.x = head4.x + tail4.x + s0.x + s1.x;
        pool.y = head4.y + tail4.y + s0.y + s1.y;
        pool.z = head4.z + tail4.z + s0.z + s1.z;
        pool.w = head4.w + tail4.w + s0.w + s1.w;

        const float4* fcW4 = (const float4*)fcW;
        float4 wg0 = fcW4[lane * 2 + 0],       wg1 = fcW4[lane * 2 + 1];
        float4 wh0 = fcW4[64 + lane * 2 + 0],  wh1 = fcW4[64 + lane * 2 + 1];
        float4 wt0 = fcW4[128 + lane * 2 + 0], wt1 = fcW4[128 + lane * 2 + 1];

        const float inv50 = 1.0f / (float)NODES_PER_G;
        float p0 = inv50 * (pool.x * wg0.x + pool.y * wg0.z + pool.z * wg1.x + pool.w * wg1.z)
                 + head4.x * wh0.x + head4.y * wh0.z + head4.z * wh1.x + head4.w * wh1.z
                 + tail4.x * wt0.x + tail4.y * wt0.z + tail4.z * wt1.x + tail4.w * wt1.z;
        float p1 = inv50 * (pool.x * wg0.y + pool.y * wg0.w + pool.z * wg1.y + pool.w * wg1.w)
                 + head4.x * wh0.y + head4.y * wh0.w + head4.z * wh1.y + head4.w * wh1.w
                 + tail4.x * wt0.y + tail4.y * wt0.w + tail4.z * wt1.y + tail4.w * wt1.w;

        // constant bias pieces: b2p·fcW[384..416) and b2·fcW[416..448)
        {
            float2 fw1 = *(const float2*)(fcW + (384 + lane) * 2);
            float2 fw2 = *(const float2*)(fcW + (416 + lane) * 2);
            float bb1 = b2p[lane], bb2 = b2[lane];
            p0 = fmaf(bb1, fw1.x, fmaf(bb2, fw2.x, p0));
            p1 = fmaf(bb1, fw1.y, fmaf(bb2, fw2.y, p1));
        }

        for (int m = 16; m >= 1; m >>= 1) {
            p0 += __shfl_xor(p0, m, 32);
            p1 += __shfl_xor(p1, m, 32);
        }
        if (lane == 0) {
            out[g * 2 + 0] = p0;   // partial: fuse dots + fc_b added by finalize
            out[g * 2 + 1] = p1;
        }
    } else if (Fb < NPF) {
        // ---------------- protein fuse ----------------
        const int p = Fb * 8 + grp;
        float m0 = 0.f, m1 = 0.f;
        #pragma unroll
        for (int k = 0; k < 32; ++k) {
            float w = W2p[lane * 32 + k];
            float2 fw = *(const float2*)(fcW + (384 + k) * 2);
            m0 = fmaf(w, fw.x, m0);
            m1 = fmaf(w, fw.y, m1);
        }
        const float4* pf4 = (const float4*)(profeat + (long)p * PFEAT);
        float a0 = 0.f, a1 = 0.f, a2 = 0.f, a3 = 0.f;
        #pragma unroll 4
        for (int q = 0; q < PFEAT / 4; q += 4) {
            float4 f0 = pf4[q], f1 = pf4[q + 1], f2 = pf4[q + 2], f3 = pf4[q + 3];
            int k = q * 4;
            a0 = fmaf(f0.x, W1p[(k + 0) * 32 + lane], a0);
            a0 = fmaf(f0.y, W1p[(k + 1) * 32 + lane], a0);
            a0 = fmaf(f0.z, W1p[(k + 2) * 32 + lane], a0);
            a0 = fmaf(f0.w, W1p[(k + 3) * 32 + lane], a0);
            a1 = fmaf(f1.x, W1p[(k + 4) * 32 + lane], a1);
            a1 = fmaf(f1.y, W1p[(k + 5) * 32 + lane], a1);
            a1 = fmaf(f1.z, W1p[(k + 6) * 32 + lane], a1);
            a1 = fmaf(f1.w, W1p[(k + 7) * 32 + lane], a1);
            a2 = fmaf(f2.x, W1p[(k + 8) * 32 + lane], a2);
            a2 = fmaf(f2.y, W1p[(k + 9) * 32 + lane], a2);
            a2 = fmaf(f2.z, W1p[(k + 10) * 32 + lane], a2);
            a2 = fmaf(f2.w, W1p[(k + 11) * 32 + lane], a2);
            a3 = fmaf(f3.x, W1p[(k + 12) * 32 + lane], a3);
            a3 = fmaf(f3.y, W1p[(k + 13) * 32 + lane], a3);
            a3 = fmaf(f3.z, W1p[(k + 14) * 32 + lane], a3);
            a3 = fmaf(f3.w, W1p[(k + 15) * 32 + lane], a3);
        }
        float h = fmaxf((a0 + a1) + (a2 + a3) + b1p[lane], 0.f);
        float p0 = h * m0, p1 = h * m1;
        for (int m = 16; m >= 1; m >>= 1) {
            p0 += __shfl_xor(p0, m, 32);
            p1 += __shfl_xor(p1, m, 32);
        }
        if (lane == 0) {
            f1out[p * 2 + 0] = p0;
            f1out[p * 2 + 1] = p1;
        }
    } else {
        // ---------------- drug fuse ----------------
        const int d = (Fb - NPF) * 8 + grp;
        float m0 = 0.f, m1 = 0.f;
        #pragma unroll
        for (int k = 0; k < 32; ++k) {
            float w = W2[lane * 32 + k];
            float2 fw = *(const float2*)(fcW + (416 + k) * 2);
            m0 = fmaf(w, fw.x, m0);
            m1 = fmaf(w, fw.y, m1);
        }
        const float4* df4 = (const float4*)(drugfeat + (long)d * FEAT);
        float a0 = 0.f, a1 = 0.f;
        #pragma unroll 5
        for (int q = 0; q < FEAT / 4; q += 2) {
            float4 f0 = df4[q], f1 = df4[q + 1];
            int k = q * 4;
            a0 = fmaf(f0.x, W1[(k + 0) * 32 + lane], a0);
            a0 = fmaf(f0.y, W1[(k + 1) * 32 + lane], a0);
            a0 = fmaf(f0.z, W1[(k + 2) * 32 + lane], a0);
            a0 = fmaf(f0.w, W1[(k + 3) * 32 + lane], a0);
            a1 = fmaf(f1.x, W1[(k + 4) * 32 + lane], a1);
            a1 = fmaf(f1.y, W1[(k + 5) * 32 + lane], a1);
            a1 = fmaf(f1.z, W1[(k + 6) * 32 + lane], a1);
            a1 = fmaf(f1.w, W1[(k + 7) * 32 + lane], a1);
        }
        float h = fmaxf(a0 + a1 + b1[lane], 0.f);
        float p0 = h * m0, p1 = h * m1;
        for (int m = 16; m >= 1; m >>= 1) {
            p0 += __shfl_xor(p0, m, 32);
            p1 += __shfl_xor(p1, m, 32);
        }
        if (lane == 0) {
            f2out[d * 2 + 0] = p0;
            f2out[d * 2 + 1] = p1;
        }
    }
}

// ---------------------------------------------------------------------------
// Finalize: one thread per graph. Dedup-table gathers + constant bias.
// ---------------------------------------------------------------------------
__global__ __launch_bounds__(256) void finalize_kernel(
    const int*   __restrict__ head_ids,  // [B]
    const int*   __restrict__ tail_ids,  // [B]
    const int*   __restrict__ node_idx,  // [N]
    const int*   __restrict__ proind,    // [I]
    const int*   __restrict__ drugind,   // [I]
    const float* __restrict__ f1out,     // [P][2]
    const float* __restrict__ f2out,     // [D][2]
    const float* __restrict__ fcb,       // [2]
    float*       __restrict__ out)       // [B][2]
{
    const int g = blockIdx.x * 256 + threadIdx.x;
    if (g >= B_GRAPHS) return;
    const int prow = proind[node_idx[head_ids[g]]];
    const int drow = drugind[node_idx[tail_ids[g]]];
    const float2 f1v = *(const float2*)(f1out + prow * 2);
    const float2 f2v = *(const float2*)(f2out + drow * 2);
    float2 o = *(float2*)(out + g * 2);
    o.x += f1v.x + f2v.x + fcb[0];
    o.y += f1v.y + f2v.y + fcb[1];
    *(float2*)(out + g * 2) = o;
}

extern "C" void kernel_launch(void* const* d_in, const int* in_sizes, int n_in,
                              void* d_out, int out_size, void* d_ws, size_t ws_size,
                              hipStream_t stream) {
    const float* node_repr = (const float*)d_in[0];
    const float* profeat   = (const float*)d_in[1];
    const float* drugfeat  = (const float*)d_in[2];
    const float* W1p       = (const float*)d_in[3];
    const float* b1p       = (const float*)d_in[4];
    const float* W2p       = (const float*)d_in[5];
    const float* b2p       = (const float*)d_in[6];
    const float* W1        = (const float*)d_in[7];
    const float* b1        = (const float*)d_in[8];
    const float* W2        = (const float*)d_in[9];
    const float* b2        = (const float*)d_in[10];
    const float* fc_W      = (const float*)d_in[11];
    const float* fc_b      = (const float*)d_in[12];
    // d_in[13] = graph_ids (unused: blocks are contiguous, 50 nodes each)
    const int* head_ids    = (const int*)d_in[14];
    const int* tail_ids    = (const int*)d_in[15];
    const int* node_idx    = (const int*)d_in[16];
    const int* proind      = (const int*)d_in[17];
    const int* drugind     = (const int*)d_in[18];

    float* f1out = (float*)d_ws;                 // 2000*2 floats
    float* f2out = (float*)d_ws + 2 * P_ROWS;    // 10000*2 floats
    float* out   = (float*)d_out;

    hipLaunchKernelGGL(merged_kernel, dim3(NTOT), dim3(256), 0, stream,
                       node_repr, profeat, drugfeat, W1p, b1p, W2p, W1, b1, W2,
                       fc_W, b2p, b2, f1out, f2out, out);

    hipLaunchKernelGGL(finalize_kernel, dim3(B_GRAPHS / 256), dim3(256), 0, stream,
                       head_ids, tail_ids, node_idx, proind, drugind,
                       f1out, f2out, fc_b, out);
}